// Round 1
// 197.851 us; speedup vs baseline: 1.0480x; 1.0480x over previous
//
#include <hip/hip_runtime.h>

typedef __bf16 bf16x8 __attribute__((ext_vector_type(8)));
typedef float f32x4 __attribute__((ext_vector_type(4)));
typedef unsigned short ushort8 __attribute__((ext_vector_type(8)));

#define BATCH 8
#define SEQ 4096
#define DH 128
#define PSTR 40
#define SC (0.08838834764831845f * 1.4426950408889634f)

// Dynamic-LDS map (u16 units):
//   K tiles : (kh*2+buf)*4096          [0     .. 16383]  32 rows x 128 u16, XOR-swizzled (byte ^= (row&7)<<4)
//   V tiles : OFF_V + (kh*2+buf)*4096  [16384 .. 32767]  128 d-rows x 32 u16, linear (bank-balanced)
//   P       : OFF_P + wv*1280          [32768 .. 37887]
#define OFF_V 16384
#define OFF_P 32768
#define SMEM_BYTES 75776   // 37888 u16 ; x2 blocks/CU = 151.5 KB <= 160 KB
#define LBUF_BYTE 36864    // epilogue l-buffer; Om region ends <= 36864

__device__ __forceinline__ unsigned short f2bf(float x) {
    unsigned int u = __builtin_bit_cast(unsigned int, x);
    u = (u + 0x7FFFu + ((u >> 16) & 1u)) >> 16;
    return (unsigned short)u;
}
__device__ __forceinline__ ushort8 cvt8(const float* __restrict__ p) {
    f32x4 a = *(const f32x4*)p;
    f32x4 b = *(const f32x4*)(p + 4);
    ushort8 r;
    r[0] = f2bf(a[0]); r[1] = f2bf(a[1]); r[2] = f2bf(a[2]); r[3] = f2bf(a[3]);
    r[4] = f2bf(b[0]); r[5] = f2bf(b[1]); r[6] = f2bf(b[2]); r[7] = f2bf(b[3]);
    return r;
}
__device__ __forceinline__ bf16x8 ldb(const unsigned short* p) {
    return __builtin_bit_cast(bf16x8, *(const ushort8*)p);
}
__device__ __forceinline__ void gll16(const void* src, void* dst) {
    // direct global->LDS, 16B per lane; LDS dest = wave-uniform base + lane*16
    __builtin_amdgcn_global_load_lds((const __attribute__((address_space(1))) unsigned int*)src,
                                     (__attribute__((address_space(3))) unsigned int*)dst, 16, 0, 0);
}

// ---------------- merged prep kernel (1 launch): K->bf16, V->bf16 transposed ----------------
__global__ __launch_bounds__(256) void prep_all(const float* __restrict__ Kg,
                                                const float* __restrict__ Vg,
                                                unsigned short* __restrict__ Kbf,
                                                unsigned short* __restrict__ Vtg) {
    __shared__ float T[32 * 36];
    if (blockIdx.x < 2048) {
        size_t i = ((size_t)blockIdx.x * 256 + threadIdx.x) * 8;
        *(ushort8*)(Kbf + i) = cvt8(Kg + i);
        return;
    }
    const int bid = blockIdx.x - 2048;
    const int b  = bid >> 9;
    const int kt = (bid >> 2) & 127;
    const int dt = bid & 3;
    const int tid = threadIdx.x;
    {
        int r = tid >> 3, c4 = (tid & 7) * 4;
        f32x4 v = *(const f32x4*)(Vg + ((size_t)b * SEQ + kt * 32 + r) * DH + dt * 32 + c4);
        *(f32x4*)(&T[r * 36 + c4]) = v;
    }
    __syncthreads();
    {
        int rd = tid >> 3, kc4 = (tid & 7) * 4;
        unsigned long long w = 0;
#pragma unroll
        for (int j = 0; j < 4; ++j)
            w |= (unsigned long long)f2bf(T[(kc4 + j) * 36 + rd]) << (16 * j);
        *(unsigned long long*)(Vtg + ((size_t)b * DH + dt * 32 + rd) * SEQ + kt * 32 + kc4) = w;
    }
}

// ---------------- staging ----------------
// PREP path: 8 x global_load_lds per wave per step (4 K-chunks + 4 V-chunks, 1KB each).
// K swizzle lives in the per-lane SOURCE address; LDS dest stays linear (gll requirement).
__device__ __forceinline__ void issue_stage(const unsigned short* __restrict__ Kbf,
                                            const unsigned short* __restrict__ Vtg,
                                            unsigned short* sm16, int b, int kh, int qh,
                                            int lane, int t)
{
    const int buf = t & 1;
    const int kb  = kh * 2048 + t * 32;
    const int rin = lane >> 4;             // 0..3
    const int sb  = (lane & 15) << 4;      // byte col within row, 16B granular
    const unsigned short* Kb = Kbf + (size_t)b * SEQ * DH;
#pragma unroll
    for (int ch = 0; ch < 4; ++ch) {
        const int row = qh * 16 + ch * 4 + rin;
        const unsigned char* src =
            (const unsigned char*)(Kb + (size_t)(kb + row) * DH) + (sb ^ ((row & 7) << 4));
        unsigned short* dst = sm16 + (kh * 2 + buf) * 4096 + (qh * 16 + ch * 4) * 128;
        gll16(src, dst);
    }
    const unsigned short* Vb = Vtg + (size_t)b * DH * SEQ;
    const int vr = lane >> 2, vk = (lane & 3) * 8;
#pragma unroll
    for (int ch = 0; ch < 4; ++ch) {
        const int row = qh * 64 + ch * 16 + vr;
        const unsigned short* src = Vb + (size_t)row * SEQ + kb + vk;
        unsigned short* dst = sm16 + OFF_V + (kh * 2 + buf) * 4096 + (qh * 64 + ch * 16) * 32;
        gll16(src, dst);
    }
}

// fallback (ws too small): fp32 loads + cvt, ds_write to the SAME layouts. Correctness only.
__device__ __forceinline__ void stage_fallback(const float* __restrict__ Kg,
                                               const float* __restrict__ Vg,
                                               unsigned short* sm16, int b, int tid, int t)
{
    const int buf = t & 1;
#pragma unroll
    for (int s = 0; s < 2; ++s) {
        const int kb = s * 2048 + t * 32;
        {   // K: 32 rows x 128 u16, swizzled
            int r = tid >> 3, cg = tid & 7;
            const float* sp = Kg + ((size_t)b * SEQ + kb + r) * DH + cg * 16;
            ushort8 lo = cvt8(sp), hi = cvt8(sp + 8);
            unsigned char* kd = (unsigned char*)(sm16 + (s * 2 + buf) * 4096) + r * 256;
            int sbb = cg * 32, m = (r & 7) << 4;
            *(ushort8*)(kd + (sbb ^ m))        = lo;
            *(ushort8*)(kd + ((sbb + 16) ^ m)) = hi;
        }
        {   // V^T: 128 d-rows x 32 keys, plain transpose (slow strided loads)
            int d = tid >> 1, half = tid & 1;
            ushort8 a, c;
#pragma unroll
            for (int j = 0; j < 8; ++j) {
                a[j] = f2bf(Vg[((size_t)b * SEQ + kb + half * 16 + j) * DH + d]);
                c[j] = f2bf(Vg[((size_t)b * SEQ + kb + half * 16 + 8 + j) * DH + d]);
            }
            unsigned short* vd = sm16 + OFF_V + (s * 2 + buf) * 4096 + d * 32 + half * 16;
            *(ushort8*)vd       = a;
            *(ushort8*)(vd + 8) = c;
        }
    }
}

// ---------------- main attention ----------------
template<int TR, int PREP>
__device__ __forceinline__ void attn_body(
    const float* __restrict__ Qg, const float* __restrict__ Kg,
    const float* __restrict__ Vg,
    const unsigned short* __restrict__ Kbf, const unsigned short* __restrict__ Vtg,
    float* __restrict__ Og, unsigned short* sm16, int b, int qt5)
{
    const int tid  = threadIdx.x;
    const int wv   = tid >> 6;
    const int lane = tid & 63;
    const int l16  = lane & 15;
    const int quad = lane >> 4;
    const int qh = wv & 1;        // q-half of the block (32 q each)
    const int kh = wv >> 1;       // key-half stream (2048 keys each)

    const size_t qbase = (size_t)b * SEQ + (size_t)qt5 * 64 + qh * 32;

    // Q fragments: A[m=q=l16][k=quad*8+j], 2 q-subtiles x 4 d-chunks
    bf16x8 qf[2][4];
#pragma unroll
    for (int qt = 0; qt < 2; ++qt) {
        const float* qp = Qg + (qbase + qt * 16 + l16) * DH + quad * 8;
#pragma unroll
        for (int c = 0; c < 4; ++c)
            qf[qt][c] = __builtin_bit_cast(bf16x8, cvt8(qp + c * 32));
    }

    const f32x4 vzero = {0.f, 0.f, 0.f, 0.f};
    f32x4 oacc[2][8];
#pragma unroll
    for (int qt = 0; qt < 2; ++qt)
#pragma unroll
        for (int c = 0; c < 8; ++c) oacc[qt][c] = vzero;
    float lp[2][4] = {{0.f,0.f,0.f,0.f},{0.f,0.f,0.f,0.f}};

    unsigned short* Pw = sm16 + OFF_P + wv * 1280;
    const int swzm = (l16 & 7) << 4;    // K read-side XOR, same for rows l16 and 16+l16

    // drain Q loads so the counted-vmcnt discipline below starts clean
    asm volatile("s_waitcnt vmcnt(0)" ::: "memory");

    // prologue: stage tile 0 into buf 0
    if (PREP) issue_stage(Kbf, Vtg, sm16, b, kh, qh, lane, 0);
    else      stage_fallback(Kg, Vg, sm16, b, tid, 0);

    for (int t = 0; t < 64; ++t) {
        __builtin_amdgcn_s_barrier();          // B1: all compute(t-1) tile reads done
        asm volatile("" ::: "memory");
        if (PREP) {
            if (t < 63) {
                issue_stage(Kbf, Vtg, sm16, b, kh, qh, lane, t + 1);
                // 8 newest (tile t+1) stay in flight across the barrier; tile t drained
                asm volatile("s_waitcnt vmcnt(8)" ::: "memory");
            } else {
                asm volatile("s_waitcnt vmcnt(0)" ::: "memory");
            }
        } else {
            if (t < 63) stage_fallback(Kg, Vg, sm16, b, tid, t + 1);
            asm volatile("s_waitcnt vmcnt(0) lgkmcnt(0)" ::: "memory");
        }
        __builtin_amdgcn_s_barrier();          // B2: tile t visible to all waves
        asm volatile("" ::: "memory");

        const unsigned char*  Kbb = (const unsigned char*)(sm16 + (kh * 2 + (t & 1)) * 4096);
        const unsigned short* Vt  = sm16 + OFF_V + (kh * 2 + (t & 1)) * 4096;

        // ---- S = Q*K^T (32q x 32key): B-frags shared across q-subtiles
        f32x4 s[2][2] = {{vzero, vzero}, {vzero, vzero}};
#pragma unroll
        for (int c = 0; c < 4; ++c) {
            bf16x8 k0 = ldb((const unsigned short*)(Kbb + l16 * 256        + ((c * 64 + quad * 16) ^ swzm)));
            bf16x8 k1 = ldb((const unsigned short*)(Kbb + (16 + l16) * 256 + ((c * 64 + quad * 16) ^ swzm)));
#pragma unroll
            for (int qt = 0; qt < 2; ++qt) {
                s[qt][0] = __builtin_amdgcn_mfma_f32_16x16x32_bf16(qf[qt][c], k0, s[qt][0], 0, 0, 0);
                s[qt][1] = __builtin_amdgcn_mfma_f32_16x16x32_bf16(qf[qt][c], k1, s[qt][1], 0, 0, 0);
            }
        }

        // ---- P = exp2(S*SC); write per-wave P [q 0..31][key 0..31]
#pragma unroll
        for (int qt = 0; qt < 2; ++qt)
#pragma unroll
            for (int ks = 0; ks < 2; ++ks)
#pragma unroll
                for (int r = 0; r < 4; ++r) {
                    float p = exp2f(s[qt][ks][r] * SC);
                    if (TR == 0) {
                        lp[qt][r] += p;
                        Pw[(qt * 16 + quad * 4 + r) * PSTR + ks * 16 + l16] = f2bf(p);
                    } else {
                        lp[qt][0] += p;
                        Pw[(qt * 16 + l16) * PSTR + ks * 16 + quad * 4 + r] = f2bf(p);
                    }
                }
        asm volatile("s_waitcnt lgkmcnt(0)" ::: "memory");   // wave-local P fence

        // ---- O += P*V : A = P[q][k=quad*8+j], B = V^T[d][key]
        bf16x8 pf0 = ldb(Pw + (l16     ) * PSTR + quad * 8);
        bf16x8 pf1 = ldb(Pw + (16 + l16) * PSTR + quad * 8);
#pragma unroll
        for (int c = 0; c < 8; ++c) {
            int d = c * 16 + l16;
            bf16x8 vf = ldb(Vt + d * 32 + quad * 8);
            oacc[0][c] = __builtin_amdgcn_mfma_f32_16x16x32_bf16(pf0, vf, oacc[0][c], 0, 0, 0);
            oacc[1][c] = __builtin_amdgcn_mfma_f32_16x16x32_bf16(pf1, vf, oacc[1][c], 0, 0, 0);
        }
    }

    // ---- key-half merge: kh=1 dumps numerator+l, kh=0 combines & stores
    float* Om   = (float*)sm16;
    float* lbuf = (float*)((char*)sm16 + LBUF_BYTE);
    __syncthreads();
    if (kh == 1) {
        if (TR == 0) {
#pragma unroll
            for (int qt = 0; qt < 2; ++qt)
#pragma unroll
                for (int c = 0; c < 8; ++c)
                    *(f32x4*)&Om[qh * 4608 + (c * 16 + l16) * 36 + qt * 16 + quad * 4] = oacc[qt][c];
#pragma unroll
            for (int qt = 0; qt < 2; ++qt)
#pragma unroll
                for (int r = 0; r < 4; ++r) {
                    float L = lp[qt][r];
                    L += __shfl_xor(L, 1); L += __shfl_xor(L, 2);
                    L += __shfl_xor(L, 4); L += __shfl_xor(L, 8);
                    if (l16 == 0) lbuf[qh * 32 + qt * 16 + quad * 4 + r] = L;
                }
        } else {
#pragma unroll
            for (int qt = 0; qt < 2; ++qt)
#pragma unroll
                for (int c = 0; c < 8; ++c)
                    *(f32x4*)&Om[qh * 4224 + (qt * 16 + l16) * 132 + c * 16 + quad * 4] = oacc[qt][c];
#pragma unroll
            for (int qt = 0; qt < 2; ++qt) {
                float L = lp[qt][0];
                L += __shfl_xor(L, 16); L += __shfl_xor(L, 32);
                if (quad == 0) lbuf[qh * 32 + qt * 16 + l16] = L;
            }
        }
    }
    __syncthreads();
    if (kh == 0) {
        if (TR == 0) {
            float Lt[2][4];
#pragma unroll
            for (int qt = 0; qt < 2; ++qt)
#pragma unroll
                for (int r = 0; r < 4; ++r) {
                    float L = lp[qt][r];
                    L += __shfl_xor(L, 1); L += __shfl_xor(L, 2);
                    L += __shfl_xor(L, 4); L += __shfl_xor(L, 8);
                    Lt[qt][r] = 1.0f / (L + lbuf[qh * 32 + qt * 16 + quad * 4 + r]);
                }
#pragma unroll
            for (int qt = 0; qt < 2; ++qt)
#pragma unroll
                for (int c = 0; c < 8; ++c) {
                    f32x4 m = *(f32x4*)&Om[qh * 4608 + (c * 16 + l16) * 36 + qt * 16 + quad * 4];
#pragma unroll
                    for (int r = 0; r < 4; ++r)
                        Og[(qbase + qt * 16 + quad * 4 + r) * DH + c * 16 + l16] =
                            (oacc[qt][c][r] + m[r]) * Lt[qt][r];
                }
        } else {
#pragma unroll
            for (int qt = 0; qt < 2; ++qt) {
                float L = lp[qt][0];
                L += __shfl_xor(L, 16); L += __shfl_xor(L, 32);
                float inv = 1.0f / (L + lbuf[qh * 32 + qt * 16 + l16]);
#pragma unroll
                for (int c = 0; c < 8; ++c) {
                    f32x4 m = *(f32x4*)&Om[qh * 4224 + (qt * 16 + l16) * 132 + c * 16 + quad * 4];
                    f32x4 o;
#pragma unroll
                    for (int r = 0; r < 4; ++r) o[r] = (oacc[qt][c][r] + m[r]) * inv;
                    *(f32x4*)&Og[(qbase + qt * 16 + l16) * DH + c * 16 + quad * 4] = o;
                }
            }
        }
    }
}

__global__ __launch_bounds__(256, 2)
void attn_fwd(const float* __restrict__ Qg, const float* __restrict__ Kg,
              const float* __restrict__ Vg,
              const unsigned short* __restrict__ Kbf,
              const unsigned short* __restrict__ Vtg,
              float* __restrict__ Og, int prep)
{
    extern __shared__ __align__(16) unsigned char smem[];
    unsigned short* sm16 = (unsigned short*)smem;

    const int lane = threadIdx.x & 63;
    const int l16  = lane & 15;

    // orientation probe: A[m][k]=m, B=1/32 -> D[m][n]=m. lane21 reg0: 4.0 vs 5.0
    ushort8 pa, pb;
    unsigned short mv = f2bf((float)l16), ov = f2bf(0.03125f);
#pragma unroll
    for (int j = 0; j < 8; ++j) { pa[j] = mv; pb[j] = ov; }
    f32x4 pz = {0.f, 0.f, 0.f, 0.f};
    f32x4 pd = __builtin_amdgcn_mfma_f32_16x16x32_bf16(
        __builtin_bit_cast(bf16x8, pa), __builtin_bit_cast(bf16x8, pb), pz, 0, 0, 0);
    const bool tr = (__shfl(pd[0], 21) > 4.5f);

    const int b   = blockIdx.x & 7;     // batch == XCD slot (L2 locality)
    const int qt5 = blockIdx.x >> 3;    // 0..63 (64 q-rows each)

    if (prep) {
        if (!tr) attn_body<0,1>(Qg, Kg, Vg, Kbf, Vtg, Og, sm16, b, qt5);
        else     attn_body<1,1>(Qg, Kg, Vg, Kbf, Vtg, Og, sm16, b, qt5);
    } else {
        if (!tr) attn_body<0,0>(Qg, Kg, Vg, Kbf, Vtg, Og, sm16, b, qt5);
        else     attn_body<1,0>(Qg, Kg, Vg, Kbf, Vtg, Og, sm16, b, qt5);
    }
}

extern "C" void kernel_launch(void* const* d_in, const int* in_sizes, int n_in,
                              void* d_out, int out_size, void* d_ws, size_t ws_size,
                              hipStream_t stream) {
    const float* Q = (const float*)d_in[0];
    const float* K = (const float*)d_in[1];
    const float* V = (const float*)d_in[2];
    float* O = (float*)d_out;

    const size_t nelem = (size_t)BATCH * SEQ * DH;        // 4,194,304
    const bool prep = (ws_size >= nelem * 2 * 2);          // 16.8 MB for Kbf + Vtg
    unsigned short* Kbf = (unsigned short*)d_ws;
    unsigned short* Vtg = Kbf + nelem;

    static int smem_cfged = 0;
    if (!smem_cfged) {
        (void)hipFuncSetAttribute((const void*)attn_fwd,
                                  hipFuncAttributeMaxDynamicSharedMemorySize, SMEM_BYTES);
        smem_cfged = 1;
    }

    if (prep)
        prep_all<<<dim3(2048 + BATCH * 128 * 4), 256, 0, stream>>>(K, V, Kbf, Vtg);
    attn_fwd<<<dim3(BATCH * (SEQ / 64)), 256, SMEM_BYTES, stream>>>(Q, K, V, Kbf, Vtg, O, prep ? 1 : 0);
}